// Round 1
// baseline (1431.222 us; speedup 1.0000x reference)
//
#include <hip/hip_runtime.h>
#include <cmath>

#define TOKENS 2048
#define DMODEL 2048
#define DHID   5632
#define NEXP   8
#define RANK   16
#define LALPHA 2.0f

typedef __attribute__((ext_vector_type(4))) float f32x4;
typedef __attribute__((ext_vector_type(8))) short s16x8;

__device__ __forceinline__ short f2bf(float f){
  unsigned u = __float_as_uint(f);
  u += 0x7fffu + ((u >> 16) & 1u);
  return (short)(u >> 16);
}
__device__ __forceinline__ float bf2f(short h){
  return __uint_as_float(((unsigned)(unsigned short)h) << 16);
}

// Load 16 consecutive fp32, convert to bf16, store 16 shorts to LDS (two b128 writes).
__device__ __forceinline__ void stage16(const float* __restrict__ src, short* __restrict__ dst){
  const float4* p = (const float4*)src;
  float4 a = p[0], b = p[1], c = p[2], d = p[3];
  s16x8 w0, w1;
  w0[0]=f2bf(a.x); w0[1]=f2bf(a.y); w0[2]=f2bf(a.z); w0[3]=f2bf(a.w);
  w0[4]=f2bf(b.x); w0[5]=f2bf(b.y); w0[6]=f2bf(b.z); w0[7]=f2bf(b.w);
  w1[0]=f2bf(c.x); w1[1]=f2bf(c.y); w1[2]=f2bf(c.z); w1[3]=f2bf(c.w);
  w1[4]=f2bf(d.x); w1[5]=f2bf(d.y); w1[6]=f2bf(d.z); w1[7]=f2bf(d.w);
  *(s16x8*)dst = w0;
  *(s16x8*)(dst + 8) = w1;
}

// ---------------- K1: router logits (fp32) + top-2 ----------------
__global__ void k_router(const float* __restrict__ x, const float* __restrict__ gw,
                         int* __restrict__ sel, float* __restrict__ topv){
  const int t = blockIdx.x;
  const float* xr = x + (long)t * DMODEL;
  float acc[NEXP];
  #pragma unroll
  for(int e=0;e<NEXP;e++) acc[e]=0.f;
  for(int d=threadIdx.x; d<DMODEL; d+=256){
    float xv = xr[d];
    #pragma unroll
    for(int e=0;e<NEXP;e++) acc[e] += xv * gw[e*DMODEL + d];
  }
  #pragma unroll
  for(int e=0;e<NEXP;e++){
    #pragma unroll
    for(int off=32; off; off>>=1) acc[e] += __shfl_down(acc[e], off, 64);
  }
  __shared__ float red[4][NEXP];
  const int wave = threadIdx.x>>6, lane = threadIdx.x&63;
  if(lane==0){
    #pragma unroll
    for(int e=0;e<NEXP;e++) red[wave][e]=acc[e];
  }
  __syncthreads();
  if(threadIdx.x==0){
    float lg[NEXP];
    #pragma unroll
    for(int e=0;e<NEXP;e++) lg[e]=red[0][e]+red[1][e]+red[2][e]+red[3][e];
    int i0=0;
    #pragma unroll
    for(int e=1;e<NEXP;e++) if(lg[e]>lg[i0]) i0=e;
    int i1=-1;
    #pragma unroll
    for(int e=0;e<NEXP;e++){ if(e==i0) continue; if(i1<0 || lg[e]>lg[i1]) i1=e; }
    sel[t*2+0]=i0; sel[t*2+1]=i1;
    topv[t*2+0]=lg[i0]; topv[t*2+1]=lg[i1];
  }
}

// ---------------- K2: softmax over the SEQUENCE axis (faithful to reference) ----------------
__global__ void k_softmax(const float* __restrict__ topv, float* __restrict__ cw){
  const int b = blockIdx.x >> 1, k = blockIdx.x & 1;
  const int base = b*1024;
  __shared__ float red[256];
  float v[4];
  float mx = -1e30f;
  #pragma unroll
  for(int i=0;i<4;i++){
    int s = threadIdx.x + i*256;
    v[i] = topv[(base+s)*2 + k];
    mx = fmaxf(mx, v[i]);
  }
  red[threadIdx.x]=mx; __syncthreads();
  for(int o=128;o;o>>=1){ if(threadIdx.x<o) red[threadIdx.x]=fmaxf(red[threadIdx.x],red[threadIdx.x+o]); __syncthreads(); }
  mx = red[0]; __syncthreads();
  float sum=0.f;
  #pragma unroll
  for(int i=0;i<4;i++){ v[i]=__expf(v[i]-mx); sum+=v[i]; }
  red[threadIdx.x]=sum; __syncthreads();
  for(int o=128;o;o>>=1){ if(threadIdx.x<o) red[threadIdx.x]+=red[threadIdx.x+o]; __syncthreads(); }
  const float inv = 1.f/red[0];
  #pragma unroll
  for(int i=0;i<4;i++){
    int s = threadIdx.x + i*256;
    cw[(base+s)*2+k] = v[i]*inv;
  }
}

// ---------------- K3: R_all = X @ Acat^T  (dense over all experts; N=256) ----------------
// Acat row c: e=c>>5, proj=(c>>4)&1 (0=up,1=gate), r=c&15
__global__ __launch_bounds__(256,2) void k_rank(
    const float* __restrict__ x, const float* __restrict__ upA, const float* __restrict__ gateA,
    float* __restrict__ Rall){
  __shared__ short As[128][40];
  __shared__ short Bs[128][40];
  const int c0 = blockIdx.x*128, t0 = blockIdx.y*128;
  const int tid = threadIdx.x, lane = tid&63, wave = tid>>6;
  const int wm=(wave>>1)*64, wn=(wave&1)*64, fr=lane&15, quad=lane>>4;
  f32x4 acc[4][4];
  #pragma unroll
  for(int i=0;i<4;i++)
    #pragma unroll
    for(int j=0;j<4;j++) acc[i][j] = (f32x4){0.f,0.f,0.f,0.f};
  const int sr = tid>>1, sc = (tid&1)*16;
  const float* asrc = x + (long)(t0+sr)*DMODEL + sc;
  const int c = c0 + sr;
  const int e = c>>5, pj=(c>>4)&1, r=c&15;
  const float* bsrc = (pj ? gateA : upA) + ((long)(e*RANK + r))*DMODEL + sc;
  for(int k0=0; k0<DMODEL; k0+=32){
    stage16(asrc + k0, &As[sr][sc]);
    stage16(bsrc + k0, &Bs[sr][sc]);
    __syncthreads();
    s16x8 af[4];
    #pragma unroll
    for(int i=0;i<4;i++) af[i] = *(const s16x8*)&As[wm + i*16 + fr][quad*8];
    #pragma unroll
    for(int j=0;j<4;j++){
      s16x8 bf = *(const s16x8*)&Bs[wn + j*16 + fr][quad*8];
      #pragma unroll
      for(int i=0;i<4;i++)
        acc[i][j] = __builtin_amdgcn_mfma_f32_16x16x32_bf16(af[i], bf, acc[i][j], 0,0,0);
    }
    __syncthreads();
  }
  #pragma unroll
  for(int i=0;i<4;i++)
    #pragma unroll
    for(int j=0;j<4;j++){
      const int rbase = wm + i*16 + quad*4;
      const int col = wn + j*16 + fr;
      #pragma unroll
      for(int reg=0;reg<4;reg++)
        Rall[(long)(t0+rbase+reg)*256 + c0 + col] = acc[i][j][reg];
    }
}

// ---------------- K4: base up/gate GEMM + LoRA-up/gate + silu*gate + c-scale -> ch[2][T][H] bf16 ----------------
struct K4Smem {
  union {
    struct { short A[128][40]; short Wu[128][40]; short Wg[128][40]; } st;
    struct { float rupg[128][2][32]; float uB[128][20]; float gB[128][20]; int sel[128][2]; float cw[128][2]; } ep;
  } u;
};

__global__ __launch_bounds__(256,2) void k_main(
    const float* __restrict__ x, const float* __restrict__ w_up, const float* __restrict__ w_gate,
    const float* __restrict__ upB, const float* __restrict__ gateB,
    const float* __restrict__ Rall, const int* __restrict__ sel, const float* __restrict__ cw,
    unsigned short* __restrict__ ch){
  __shared__ K4Smem sm;
  const int h0 = blockIdx.x*128, t0 = blockIdx.y*128;
  const int tid = threadIdx.x, lane = tid&63, wave = tid>>6;
  const int wm=(wave>>1)*64, wn=(wave&1)*64, fr=lane&15, quad=lane>>4;
  f32x4 au[4][4], ag[4][4];
  #pragma unroll
  for(int i=0;i<4;i++)
    #pragma unroll
    for(int j=0;j<4;j++){ au[i][j]=(f32x4){0.f,0.f,0.f,0.f}; ag[i][j]=(f32x4){0.f,0.f,0.f,0.f}; }
  const int sr = tid>>1, sc = (tid&1)*16;
  const float* asrc = x      + (long)(t0+sr)*DMODEL + sc;
  const float* usrc = w_up   + (long)(h0+sr)*DMODEL + sc;
  const float* gsrc = w_gate + (long)(h0+sr)*DMODEL + sc;
  for(int k0=0; k0<DMODEL; k0+=32){
    stage16(asrc + k0, &sm.u.st.A[sr][sc]);
    stage16(usrc + k0, &sm.u.st.Wu[sr][sc]);
    stage16(gsrc + k0, &sm.u.st.Wg[sr][sc]);
    __syncthreads();
    s16x8 af[4];
    #pragma unroll
    for(int i=0;i<4;i++) af[i] = *(const s16x8*)&sm.u.st.A[wm + i*16 + fr][quad*8];
    #pragma unroll
    for(int j=0;j<4;j++){
      s16x8 bu = *(const s16x8*)&sm.u.st.Wu[wn + j*16 + fr][quad*8];
      s16x8 bg = *(const s16x8*)&sm.u.st.Wg[wn + j*16 + fr][quad*8];
      #pragma unroll
      for(int i=0;i<4;i++){
        au[i][j] = __builtin_amdgcn_mfma_f32_16x16x32_bf16(af[i], bu, au[i][j], 0,0,0);
        ag[i][j] = __builtin_amdgcn_mfma_f32_16x16x32_bf16(af[i], bg, ag[i][j], 0,0,0);
      }
    }
    __syncthreads();
  }
  // ---- epilogue: gather routing + rank vectors ----
  { const int tl = tid>>1, k = tid&1;
    sm.u.ep.sel[tl][k] = sel[(t0+tl)*2 + k];
    sm.u.ep.cw[tl][k]  = cw[(t0+tl)*2 + k]; }
  __syncthreads();
  for(int i2 = tid; i2 < 128*64; i2 += 256){
    const int tl = i2>>6, kk = (i2>>5)&1, rr = i2&31;
    const int e = sm.u.ep.sel[tl][kk];
    sm.u.ep.rupg[tl][kk][rr] = LALPHA * Rall[(long)(t0+tl)*256 + e*32 + rr];
  }
  for(int e=0; e<NEXP; e++){
    __syncthreads();
    for(int i2 = tid; i2 < 128*16; i2 += 256){
      const int hr = i2>>4, rr = i2&15;
      sm.u.ep.uB[hr][rr] = upB  [((long)e*DHID + h0+hr)*RANK + rr];
      sm.u.ep.gB[hr][rr] = gateB[((long)e*DHID + h0+hr)*RANK + rr];
    }
    __syncthreads();
    #pragma unroll
    for(int i=0;i<4;i++){
      #pragma unroll
      for(int reg=0;reg<4;reg++){
        const int tl = wm + i*16 + quad*4 + reg;
        #pragma unroll
        for(int k=0;k<2;k++){
          if(sm.u.ep.sel[tl][k] != e) continue;
          const float c = sm.u.ep.cw[tl][k];
          const f32x4* ru = (const f32x4*)&sm.u.ep.rupg[tl][k][0];
          const f32x4* rg = (const f32x4*)&sm.u.ep.rupg[tl][k][16];
          unsigned short* chrow = ch + ((long)k*TOKENS + (t0+tl))*DHID + h0;
          #pragma unroll
          for(int j=0;j<4;j++){
            const int hl = wn + j*16 + fr;
            const f32x4* ub = (const f32x4*)&sm.u.ep.uB[hl][0];
            const f32x4* gb = (const f32x4*)&sm.u.ep.gB[hl][0];
            f32x4 s1 = ru[0]*ub[0] + ru[1]*ub[1] + ru[2]*ub[2] + ru[3]*ub[3];
            f32x4 s2 = rg[0]*gb[0] + rg[1]*gb[1] + rg[2]*gb[2] + rg[3]*gb[3];
            const float lu = s1[0]+s1[1]+s1[2]+s1[3];
            const float lg = s2[0]+s2[1]+s2[2]+s2[3];
            const float uu = au[i][j][reg] + lu;
            const float gg = ag[i][j][reg] + lg;
            const float hv = (uu / (1.f + __expf(-uu))) * gg;
            chrow[hl] = (unsigned short)f2bf(c * hv);
          }
        }
      }
    }
  }
}

// ---------------- K5: RD[t][k][c] = sum_h ch_k[t][h] * down_A_cat[c][h]  (K-split=8, fp32 atomics) ----------------
__global__ __launch_bounds__(256,2) void k_rd(
    const unsigned short* __restrict__ ch, const float* __restrict__ downA,
    float* __restrict__ RD){
  __shared__ short As[128][40];
  __shared__ short Bs[128][40];
  const int slot = blockIdx.x>>3, ks = blockIdx.x&7;
  const int t0 = blockIdx.y*128;
  const int tid = threadIdx.x, lane = tid&63, wave = tid>>6;
  const int wm=(wave>>1)*64, wn=(wave&1)*64, fr=lane&15, quad=lane>>4;
  f32x4 acc[4][4];
  #pragma unroll
  for(int i=0;i<4;i++)
    #pragma unroll
    for(int j=0;j<4;j++) acc[i][j]=(f32x4){0.f,0.f,0.f,0.f};
  const int sr = tid>>1, sc = (tid&1)*16;
  const unsigned short* asrc = ch + ((long)slot*TOKENS + t0+sr)*DHID + sc;
  const float* bsrc = downA + (long)sr*DHID + sc;  // downA viewed as [128][DHID]
  const int kbeg = ks*704, kend = kbeg+704;
  for(int k0=kbeg; k0<kend; k0+=32){
    *(s16x8*)&As[sr][sc]   = *(const s16x8*)(asrc + k0);
    *(s16x8*)&As[sr][sc+8] = *(const s16x8*)(asrc + k0 + 8);
    stage16(bsrc + k0, &Bs[sr][sc]);
    __syncthreads();
    s16x8 af[4];
    #pragma unroll
    for(int i=0;i<4;i++) af[i] = *(const s16x8*)&As[wm + i*16 + fr][quad*8];
    #pragma unroll
    for(int j=0;j<4;j++){
      s16x8 bf = *(const s16x8*)&Bs[wn + j*16 + fr][quad*8];
      #pragma unroll
      for(int i=0;i<4;i++)
        acc[i][j] = __builtin_amdgcn_mfma_f32_16x16x32_bf16(af[i], bf, acc[i][j], 0,0,0);
    }
    __syncthreads();
  }
  #pragma unroll
  for(int i=0;i<4;i++)
    #pragma unroll
    for(int j=0;j<4;j++){
      const int rbase = wm + i*16 + quad*4;
      const int col = wn + j*16 + fr;
      #pragma unroll
      for(int reg=0;reg<4;reg++)
        atomicAdd(&RD[((long)(t0+rbase+reg)*2 + slot)*128 + col], acc[i][j][reg]);
    }
}

// ---------------- K6: out = (ch0+ch1) @ w_down^T + 2 * rd . down_B[e]  ----------------
struct K6Smem {
  union {
    struct { short A[128][40]; short B[128][40]; } st;
    struct { float rd[128][2][16]; float dB[128][20]; int sel[128][2]; } ep;
  } u;
};

__global__ __launch_bounds__(256,2) void k_down(
    const unsigned short* __restrict__ ch, const float* __restrict__ w_down,
    const float* __restrict__ RD, const float* __restrict__ downB,
    const int* __restrict__ sel, float* __restrict__ out){
  __shared__ K6Smem sm;
  const int d0 = blockIdx.x*128, t0 = blockIdx.y*128;
  const int tid = threadIdx.x, lane = tid&63, wave = tid>>6;
  const int wm=(wave>>1)*64, wn=(wave&1)*64, fr=lane&15, quad=lane>>4;
  f32x4 acc[4][4];
  #pragma unroll
  for(int i=0;i<4;i++)
    #pragma unroll
    for(int j=0;j<4;j++) acc[i][j]=(f32x4){0.f,0.f,0.f,0.f};
  const int sr = tid>>1, sc = (tid&1)*16;
  const unsigned short* a0 = ch + ((long)(t0+sr))*DHID + sc;
  const unsigned short* a1 = ch + ((long)(TOKENS + t0+sr))*DHID + sc;
  const float* bsrc = w_down + (long)(d0+sr)*DHID + sc;
  for(int k0=0; k0<DHID; k0+=32){
    s16x8 p0 = *(const s16x8*)(a0 + k0);
    s16x8 p1 = *(const s16x8*)(a0 + k0 + 8);
    s16x8 q0 = *(const s16x8*)(a1 + k0);
    s16x8 q1 = *(const s16x8*)(a1 + k0 + 8);
    s16x8 m0, m1;
    #pragma unroll
    for(int m=0;m<8;m++){ m0[m]=f2bf(bf2f(p0[m])+bf2f(q0[m])); m1[m]=f2bf(bf2f(p1[m])+bf2f(q1[m])); }
    *(s16x8*)&sm.u.st.A[sr][sc]   = m0;
    *(s16x8*)&sm.u.st.A[sr][sc+8] = m1;
    stage16(bsrc + k0, &sm.u.st.B[sr][sc]);
    __syncthreads();
    s16x8 af[4];
    #pragma unroll
    for(int i=0;i<4;i++) af[i] = *(const s16x8*)&sm.u.st.A[wm + i*16 + fr][quad*8];
    #pragma unroll
    for(int j=0;j<4;j++){
      s16x8 bf = *(const s16x8*)&sm.u.st.B[wn + j*16 + fr][quad*8];
      #pragma unroll
      for(int i=0;i<4;i++)
        acc[i][j] = __builtin_amdgcn_mfma_f32_16x16x32_bf16(af[i], bf, acc[i][j], 0,0,0);
    }
    __syncthreads();
  }
  // ---- epilogue: add down-LoRA ----
  { const int tl = tid>>1, k = tid&1;
    sm.u.ep.sel[tl][k] = sel[(t0+tl)*2 + k]; }
  __syncthreads();
  for(int i2 = tid; i2 < 128*32; i2 += 256){
    const int tl = i2>>5, kk = (i2>>4)&1, rr = i2&15;
    const int e = sm.u.ep.sel[tl][kk];
    sm.u.ep.rd[tl][kk][rr] = RD[((long)(t0+tl)*2 + kk)*128 + e*16 + rr];
  }
  for(int e=0; e<NEXP; e++){
    __syncthreads();
    for(int i2 = tid; i2 < 128*16; i2 += 256){
      const int dr = i2>>4, rr = i2&15;
      sm.u.ep.dB[dr][rr] = downB[((long)e*DMODEL + d0+dr)*RANK + rr];
    }
    __syncthreads();
    #pragma unroll
    for(int i=0;i<4;i++){
      #pragma unroll
      for(int reg=0;reg<4;reg++){
        const int tl = wm + i*16 + quad*4 + reg;
        #pragma unroll
        for(int k=0;k<2;k++){
          if(sm.u.ep.sel[tl][k] != e) continue;
          const f32x4* rd4 = (const f32x4*)&sm.u.ep.rd[tl][k][0];
          #pragma unroll
          for(int j=0;j<4;j++){
            const int dl = wn + j*16 + fr;
            const f32x4* db = (const f32x4*)&sm.u.ep.dB[dl][0];
            f32x4 s = rd4[0]*db[0] + rd4[1]*db[1] + rd4[2]*db[2] + rd4[3]*db[3];
            acc[i][j][reg] += LALPHA*(s[0]+s[1]+s[2]+s[3]);
          }
        }
      }
    }
  }
  #pragma unroll
  for(int i=0;i<4;i++)
    #pragma unroll
    for(int j=0;j<4;j++){
      const int rbase = wm + i*16 + quad*4;
      const int col = wn + j*16 + fr;
      #pragma unroll
      for(int reg=0;reg<4;reg++)
        out[(long)(t0+rbase+reg)*DMODEL + d0 + col] = acc[i][j][reg];
    }
}

extern "C" void kernel_launch(void* const* d_in, const int* in_sizes, int n_in,
                              void* d_out, int out_size, void* d_ws, size_t ws_size,
                              hipStream_t stream){
  (void)in_sizes; (void)n_in; (void)out_size; (void)ws_size;
  const float* x      = (const float*)d_in[0];
  const float* gate_w = (const float*)d_in[1];
  const float* w_up   = (const float*)d_in[2];
  const float* w_gate = (const float*)d_in[3];
  const float* w_down = (const float*)d_in[4];
  const float* up_A   = (const float*)d_in[5];
  const float* up_B   = (const float*)d_in[6];
  const float* gate_A = (const float*)d_in[7];
  const float* gate_B = (const float*)d_in[8];
  const float* down_A = (const float*)d_in[9];
  const float* down_B = (const float*)d_in[10];
  float* out = (float*)d_out;

  char* ws = (char*)d_ws;
  size_t off = 0;
  unsigned short* ch = (unsigned short*)(ws + off); off += (size_t)2*TOKENS*DHID*2;   // 46.1 MB bf16
  float* Rall = (float*)(ws + off); off += (size_t)TOKENS*256*4;                       // 2 MB
  float* RD   = (float*)(ws + off); off += (size_t)TOKENS*2*128*4;                     // 2 MB
  int*   sel  = (int*)(ws + off);   off += (size_t)TOKENS*2*4;
  float* topv = (float*)(ws + off); off += (size_t)TOKENS*2*4;
  float* cw   = (float*)(ws + off); off += (size_t)TOKENS*2*4;

  hipMemsetAsync(RD, 0, (size_t)TOKENS*2*128*4, stream);
  k_router<<<TOKENS, 256, 0, stream>>>(x, gate_w, sel, topv);
  k_softmax<<<4, 256, 0, stream>>>(topv, cw);
  k_rank<<<dim3(2,16), 256, 0, stream>>>(x, up_A, gate_A, Rall);
  k_main<<<dim3(44,16), 256, 0, stream>>>(x, w_up, w_gate, up_B, gate_B, Rall, sel, cw, ch);
  k_rd<<<dim3(16,16), 256, 0, stream>>>(ch, down_A, RD);
  k_down<<<dim3(16,16), 256, 0, stream>>>(ch, w_down, RD, down_B, sel, out);
}

// Round 3
// 611.845 us; speedup vs baseline: 2.3392x; 2.3392x over previous
//
#include <hip/hip_runtime.h>
#include <hip/hip_fp16.h>
#include <cmath>

#define TOKENS 2048
#define DMODEL 2048
#define DHID   5632
#define NEXP   8
#define RANK   16
#define LALPHA 2.0f

typedef __attribute__((ext_vector_type(4))) float f32x4;
typedef __attribute__((ext_vector_type(8))) short s16x8;
typedef __attribute__((ext_vector_type(4))) short s16x4;
typedef __attribute__((ext_vector_type(8))) _Float16 f16x8;

__device__ __forceinline__ short f2bf(float f){
  unsigned u = __float_as_uint(f);
  u += 0x7fffu + ((u >> 16) & 1u);
  return (short)(u >> 16);
}

// ---------- async global->LDS staging of a 128x32 bf16/f16 tile ----------
// LDS tile = 512 slots of 16B, linear. slot L: row r=L>>2, phys chunk p=L&3.
// Logical k-chunk c stored at p=(c+(r>>1))&3  => frag reads hit 8 distinct
// bank groups per 16-lane quad (2-way aliasing only = free).
struct Stage { const short* s0; const short* s1; short* d0; short* d1; };

__device__ __forceinline__ Stage mk_stage(const short* g, long ld, short* t, int tid){
  Stage st;
  const int L0 = tid,      r0 = L0>>2, c0 = ((L0&3) - (r0>>1)) & 3;
  const int L1 = 256+tid,  r1 = L1>>2, c1 = ((L1&3) - (r1>>1)) & 3;
  st.s0 = g + (long)r0*ld + c0*8;  st.d0 = t + L0*8;
  st.s1 = g + (long)r1*ld + c1*8;  st.d1 = t + L1*8;
  return st;
}
__device__ __forceinline__ void do_stage(const Stage& st, int k0){
  __builtin_amdgcn_global_load_lds((const __attribute__((address_space(1))) void*)(st.s0 + k0),
                                   (__attribute__((address_space(3))) void*)st.d0, 16, 0, 0);
  __builtin_amdgcn_global_load_lds((const __attribute__((address_space(1))) void*)(st.s1 + k0),
                                   (__attribute__((address_space(3))) void*)st.d1, 16, 0, 0);
}
__device__ __forceinline__ s16x8 fragb(const short* t, int row, int quad){
  const int p = (quad + (row>>1)) & 3;
  return *(const s16x8*)(t + (row*4 + p)*8);
}
__device__ __forceinline__ f16x8 fragh(const short* t, int row, int quad){
  const int p = (quad + (row>>1)) & 3;
  return *(const f16x8*)(t + (row*4 + p)*8);
}

// ---------------- K0: cast/gather all GEMM operands ----------------
__global__ void k_cast(const float* __restrict__ x, const float* __restrict__ w_up,
                       const float* __restrict__ w_gate, const float* __restrict__ w_down,
                       const float* __restrict__ upA, const float* __restrict__ gateA,
                       const float* __restrict__ downA, const float* __restrict__ upB,
                       const float* __restrict__ gateB, const float* __restrict__ downB,
                       short* __restrict__ xb, short* __restrict__ wub, short* __restrict__ wgb,
                       short* __restrict__ wdb, short* __restrict__ acat, short* __restrict__ daA,
                       short* __restrict__ upBh, short* __restrict__ gateBh, short* __restrict__ wdbcat){
  const long e0 = 4194304, e1 = 15728640, e2 = 27262976, e3 = 38797312;
  const long e4 = 39518208, e5 = 40239104, e6 = 40960000, e7 = 41484288, e8 = 41746432;
  const long i = ((long)blockIdx.x*256 + threadIdx.x) * 4;
  if(i >= e8) return;
  const float* src; short* dst; long l; int fp16 = 0;
  if(i < e0){ src = x; dst = xb; l = i; }
  else if(i < e1){ src = w_up; dst = wub; l = i - e0; }
  else if(i < e2){ src = w_gate; dst = wgb; l = i - e1; }
  else if(i < e3){ src = w_down; dst = wdb; l = i - e2; }
  else if(i < e4){ src = downA; dst = daA; l = i - e3; }
  else if(i < e5){ src = upB; dst = upBh; l = i - e4; fp16 = 1; }
  else if(i < e6){ src = gateB; dst = gateBh; l = i - e5; fp16 = 1; }
  else if(i < e7){ // acat[c][d] = (pj?gateA:upA)[e][r][d], c = e*32+pj*16+r
    l = i - e6;
    const long c = l>>11, d = l&2047;
    const long e = c>>5, pj = (c>>4)&1, r = c&15;
    src = (pj ? gateA : upA) + ((e*RANK + r)<<11) + d - l;  // so src+l is right
    dst = acat;
  } else { // wdbcat[d][e*16+r] = downB[e][d][r]  (f16)
    l = i - e7;
    const long d = l>>7, c = l&127;
    const long e = c>>4, r = c&15;
    src = downB + (e*DMODEL + d)*RANK + r - l;
    dst = wdbcat; fp16 = 1;
  }
  const float4 v = *(const float4*)(src + l);
  s16x4 o;
  if(fp16){
    o[0]=(short)__half_as_ushort(__float2half(v.x));
    o[1]=(short)__half_as_ushort(__float2half(v.y));
    o[2]=(short)__half_as_ushort(__float2half(v.z));
    o[3]=(short)__half_as_ushort(__float2half(v.w));
  } else {
    o[0]=f2bf(v.x); o[1]=f2bf(v.y); o[2]=f2bf(v.z); o[3]=f2bf(v.w);
  }
  *(s16x4*)(dst + l) = o;
}

// ---------------- K1: router logits (fp32, one wave per token) + top-2 ----------------
__global__ void k_router(const float* __restrict__ x, const float* __restrict__ gw,
                         int* __restrict__ sel, float* __restrict__ topv){
  const int t = blockIdx.x*4 + (threadIdx.x>>6);
  const int lane = threadIdx.x & 63;
  const float* xr = x + (long)t * DMODEL;
  float acc[NEXP];
  #pragma unroll
  for(int e=0;e<NEXP;e++) acc[e]=0.f;
  #pragma unroll
  for(int it=0; it<8; it++){
    const int d = it*256 + lane*4;
    const float4 xv = *(const float4*)(xr + d);
    #pragma unroll
    for(int e=0;e<NEXP;e++){
      const float4 wv = *(const float4*)(gw + e*DMODEL + d);
      acc[e] += xv.x*wv.x + xv.y*wv.y + xv.z*wv.z + xv.w*wv.w;
    }
  }
  #pragma unroll
  for(int e=0;e<NEXP;e++){
    #pragma unroll
    for(int off=32; off; off>>=1) acc[e] += __shfl_down(acc[e], off, 64);
  }
  if(lane==0){
    int i0=0;
    #pragma unroll
    for(int e=1;e<NEXP;e++) if(acc[e]>acc[i0]) i0=e;
    int i1=-1;
    #pragma unroll
    for(int e=0;e<NEXP;e++){ if(e==i0) continue; if(i1<0 || acc[e]>acc[i1]) i1=e; }
    sel[t*2+0]=i0; sel[t*2+1]=i1;
    topv[t*2+0]=acc[i0]; topv[t*2+1]=acc[i1];
  }
}

// ---------------- K2: softmax over the SEQUENCE axis (faithful) ----------------
__global__ void k_softmax(const float* __restrict__ topv, float* __restrict__ cw){
  const int b = blockIdx.x >> 1, k = blockIdx.x & 1;
  const int base = b*1024;
  __shared__ float red[256];
  float v[4];
  float mx = -1e30f;
  #pragma unroll
  for(int i=0;i<4;i++){
    int s = threadIdx.x + i*256;
    v[i] = topv[(base+s)*2 + k];
    mx = fmaxf(mx, v[i]);
  }
  red[threadIdx.x]=mx; __syncthreads();
  for(int o=128;o;o>>=1){ if(threadIdx.x<o) red[threadIdx.x]=fmaxf(red[threadIdx.x],red[threadIdx.x+o]); __syncthreads(); }
  mx = red[0]; __syncthreads();
  float sum=0.f;
  #pragma unroll
  for(int i=0;i<4;i++){ v[i]=__expf(v[i]-mx); sum+=v[i]; }
  red[threadIdx.x]=sum; __syncthreads();
  for(int o=128;o;o>>=1){ if(threadIdx.x<o) red[threadIdx.x]+=red[threadIdx.x+o]; __syncthreads(); }
  const float inv = 1.f/red[0];
  #pragma unroll
  for(int i=0;i<4;i++){
    int s = threadIdx.x + i*256;
    cw[(base+s)*2+k] = v[i]*inv;
  }
}

// ---------------- K3: Rall = X @ Acat^T (dense, N=256) ----------------
__global__ __launch_bounds__(256,3) void k_rank(
    const short* __restrict__ xb, const short* __restrict__ acat, float* __restrict__ Rall){
  __shared__ __align__(16) short At[4096];
  __shared__ __align__(16) short Bt[4096];
  const int c0 = blockIdx.x*128, t0 = blockIdx.y*128;
  const int tid = threadIdx.x, lane = tid&63, wave = tid>>6;
  const int wm=(wave>>1)*64, wn=(wave&1)*64, fr=lane&15, quad=lane>>4;
  f32x4 acc[4][4];
  #pragma unroll
  for(int i=0;i<4;i++)
    #pragma unroll
    for(int j=0;j<4;j++) acc[i][j]=(f32x4){0.f,0.f,0.f,0.f};
  const Stage sA = mk_stage(xb + (long)t0*DMODEL, DMODEL, At, tid);
  const Stage sB = mk_stage(acat + (long)c0*DMODEL, DMODEL, Bt, tid);
  for(int k0=0; k0<DMODEL; k0+=32){
    do_stage(sA, k0); do_stage(sB, k0);
    __syncthreads();
    s16x8 af[4];
    #pragma unroll
    for(int i=0;i<4;i++) af[i] = fragb(At, wm + i*16 + fr, quad);
    #pragma unroll
    for(int j=0;j<4;j++){
      const s16x8 bf = fragb(Bt, wn + j*16 + fr, quad);
      #pragma unroll
      for(int i=0;i<4;i++)
        acc[i][j] = __builtin_amdgcn_mfma_f32_16x16x32_bf16(af[i], bf, acc[i][j], 0,0,0);
    }
    __syncthreads();
  }
  #pragma unroll
  for(int i=0;i<4;i++)
    #pragma unroll
    for(int j=0;j<4;j++){
      const int rbase = wm + i*16 + quad*4, col = wn + j*16 + fr;
      #pragma unroll
      for(int reg=0;reg<4;reg++)
        Rall[(long)(t0+rbase+reg)*256 + c0 + col] = acc[i][j][reg];
    }
}

// ---------------- K4: base up/gate GEMM + f16 LoRA epilogue -> ch[2][T][H] bf16 ----------------
struct K4Smem {
  union {
    struct { short A[4096]; short U[4096]; short G[4096]; } st;
    struct { __half rub[128][2][32]; float cwv[128][2]; int sele[128][2]; } ep;
  } u;
};

__global__ __launch_bounds__(256,2) void k_main(
    const short* __restrict__ xb, const short* __restrict__ wub, const short* __restrict__ wgb,
    const __half* __restrict__ upBh, const __half* __restrict__ gateBh,
    const float* __restrict__ Rall, const int* __restrict__ sel, const float* __restrict__ cw,
    unsigned short* __restrict__ ch){
  __shared__ __align__(16) K4Smem sm;
  const int h0 = blockIdx.x*128, t0 = blockIdx.y*128;
  const int tid = threadIdx.x, lane = tid&63, wave = tid>>6;
  const int wm=(wave>>1)*64, wn=(wave&1)*64, fr=lane&15, quad=lane>>4;
  f32x4 au[4][4], ag[4][4];
  #pragma unroll
  for(int i=0;i<4;i++)
    #pragma unroll
    for(int j=0;j<4;j++){ au[i][j]=(f32x4){0.f,0.f,0.f,0.f}; ag[i][j]=(f32x4){0.f,0.f,0.f,0.f}; }
  const Stage sA = mk_stage(xb + (long)t0*DMODEL, DMODEL, sm.u.st.A, tid);
  const Stage sU = mk_stage(wub + (long)h0*DMODEL, DMODEL, sm.u.st.U, tid);
  const Stage sG = mk_stage(wgb + (long)h0*DMODEL, DMODEL, sm.u.st.G, tid);
  for(int k0=0; k0<DMODEL; k0+=32){
    do_stage(sA, k0); do_stage(sU, k0); do_stage(sG, k0);
    __syncthreads();
    s16x8 af[4];
    #pragma unroll
    for(int i=0;i<4;i++) af[i] = fragb(sm.u.st.A, wm + i*16 + fr, quad);
    #pragma unroll
    for(int j=0;j<4;j++){
      const s16x8 bu = fragb(sm.u.st.U, wn + j*16 + fr, quad);
      const s16x8 bg = fragb(sm.u.st.G, wn + j*16 + fr, quad);
      #pragma unroll
      for(int i=0;i<4;i++){
        au[i][j] = __builtin_amdgcn_mfma_f32_16x16x32_bf16(af[i], bu, au[i][j], 0,0,0);
        ag[i][j] = __builtin_amdgcn_mfma_f32_16x16x32_bf16(af[i], bg, ag[i][j], 0,0,0);
      }
    }
    __syncthreads();
  }
  // ---- epilogue staging: routing + alpha-scaled rank vectors (f16) ----
  for(int i2 = tid; i2 < 256; i2 += 256){
    const int tl = i2>>1, k = i2&1;
    sm.u.ep.sele[tl][k] = sel[(t0+tl)*2 + k];
    sm.u.ep.cwv[tl][k]  = cw[(t0+tl)*2 + k];
  }
  for(int i2 = tid; i2 < 128*2*32; i2 += 256){
    const int tl = i2>>6, k = (i2>>5)&1, r = i2&31;
    const int e = sel[(t0+tl)*2 + k];
    sm.u.ep.rub[tl][k][r] = __float2half(LALPHA * Rall[(long)(t0+tl)*256 + e*32 + r]);
  }
  __syncthreads();
  #pragma unroll
  for(int i=0;i<4;i++){
    #pragma unroll
    for(int reg=0;reg<4;reg++){
      const int tl = wm + i*16 + quad*4 + reg;
      #pragma unroll
      for(int k=0;k<2;k++){
        const int e = sm.u.ep.sele[tl][k];
        const float c = sm.u.ep.cwv[tl][k];
        __half2 rv[16];
        #pragma unroll
        for(int q=0;q<4;q++) *(s16x8*)&rv[q*4] = *(const s16x8*)&sm.u.ep.rub[tl][k][q*8];
        const __half* ubase = upBh   + (long)e*DHID*RANK;
        const __half* gbase = gateBh + (long)e*DHID*RANK;
        unsigned short* chrow = ch + ((long)k*TOKENS + t0+tl)*DHID + h0;
        #pragma unroll
        for(int j=0;j<4;j++){
          const int hl = wn + j*16 + fr;
          const __half2* ub = (const __half2*)(ubase + (long)(h0+hl)*RANK);
          const __half2* gb = (const __half2*)(gbase + (long)(h0+hl)*RANK);
          __half2 a2 = __half2{__half(0.f),__half(0.f)}, b2 = a2;
          #pragma unroll
          for(int r=0;r<8;r++){ a2 = __hfma2(rv[r], ub[r], a2); b2 = __hfma2(rv[8+r], gb[r], b2); }
          const float lu = __low2float(a2) + __high2float(a2);
          const float lg = __low2float(b2) + __high2float(b2);
          const float uu = au[i][j][reg] + lu;
          const float gg = ag[i][j][reg] + lg;
          const float hv = (uu / (1.f + __expf(-uu))) * gg;
          chrow[hl] = (unsigned short)f2bf(c * hv);
        }
      }
    }
  }
}

// ---------------- K5: RD[t][k][c] = ch_k @ downA_cat^T (ksplit=8, atomics) ----------------
__global__ __launch_bounds__(256,3) void k_rd(
    const unsigned short* __restrict__ ch, const short* __restrict__ daA,
    float* __restrict__ RD){
  __shared__ __align__(16) short At[4096];
  __shared__ __align__(16) short Bt[4096];
  const int slot = blockIdx.x>>3, ks = blockIdx.x&7;
  const int t0 = blockIdx.y*128;
  const int tid = threadIdx.x, lane = tid&63, wave = tid>>6;
  const int wm=(wave>>1)*64, wn=(wave&1)*64, fr=lane&15, quad=lane>>4;
  f32x4 acc[4][4];
  #pragma unroll
  for(int i=0;i<4;i++)
    #pragma unroll
    for(int j=0;j<4;j++) acc[i][j]=(f32x4){0.f,0.f,0.f,0.f};
  const Stage sA = mk_stage((const short*)ch + ((long)slot*TOKENS + t0)*DHID, DHID, At, tid);
  const Stage sB = mk_stage(daA, DHID, Bt, tid);
  const int kbeg = ks*704;
  for(int kk=0; kk<704; kk+=32){
    do_stage(sA, kbeg+kk); do_stage(sB, kbeg+kk);
    __syncthreads();
    s16x8 af[4];
    #pragma unroll
    for(int i=0;i<4;i++) af[i] = fragb(At, wm + i*16 + fr, quad);
    #pragma unroll
    for(int j=0;j<4;j++){
      const s16x8 bf = fragb(Bt, wn + j*16 + fr, quad);
      #pragma unroll
      for(int i=0;i<4;i++)
        acc[i][j] = __builtin_amdgcn_mfma_f32_16x16x32_bf16(af[i], bf, acc[i][j], 0,0,0);
    }
    __syncthreads();
  }
  #pragma unroll
  for(int i=0;i<4;i++)
    #pragma unroll
    for(int j=0;j<4;j++){
      const int rbase = wm + i*16 + quad*4, col = wn + j*16 + fr;
      #pragma unroll
      for(int reg=0;reg<4;reg++)
        atomicAdd(&RD[((long)(t0+rbase+reg)*2 + slot)*128 + col], acc[i][j][reg]);
    }
}

// ---------------- K5b: RDhat[t][c] (f16) = alpha * RD at selected expert blocks ----------------
__global__ void k_scatter(const float* __restrict__ RD, const int* __restrict__ sel,
                          __half* __restrict__ RDhat){
  const int idx = blockIdx.x*256 + threadIdx.x;   // over T*128
  const int t = idx>>7, c = idx&127, e = c>>4;
  const int s0 = sel[t*2], s1 = sel[t*2+1];
  float v = 0.f;
  if(e == s0) v = LALPHA * RD[((long)t*2+0)*128 + c];
  else if(e == s1) v = LALPHA * RD[((long)t*2+1)*128 + c];
  RDhat[idx] = __float2half(v);
}

// ---------------- K6: out = (ch0+ch1) @ wdb^T  +  RDhat @ wdbcat^T  (pure MFMA) ----------------
__global__ __launch_bounds__(256,3) void k_down(
    const unsigned short* __restrict__ ch, const short* __restrict__ wdb,
    const short* __restrict__ RDhat, const short* __restrict__ wdbcat,
    float* __restrict__ out){
  __shared__ __align__(16) short A0t[4096];
  __shared__ __align__(16) short A1t[4096];
  __shared__ __align__(16) short Bt[4096];
  const int d0 = blockIdx.x*128, t0 = blockIdx.y*128;
  const int tid = threadIdx.x, lane = tid&63, wave = tid>>6;
  const int wm=(wave>>1)*64, wn=(wave&1)*64, fr=lane&15, quad=lane>>4;
  f32x4 acc[4][4];
  #pragma unroll
  for(int i=0;i<4;i++)
    #pragma unroll
    for(int j=0;j<4;j++) acc[i][j]=(f32x4){0.f,0.f,0.f,0.f};
  const Stage sA0 = mk_stage((const short*)ch + (long)t0*DHID, DHID, A0t, tid);
  const Stage sA1 = mk_stage((const short*)ch + ((long)TOKENS + t0)*DHID, DHID, A1t, tid);
  const Stage sB  = mk_stage(wdb + (long)d0*DHID, DHID, Bt, tid);
  for(int k0=0; k0<DHID; k0+=32){
    do_stage(sA0, k0); do_stage(sA1, k0); do_stage(sB, k0);
    __syncthreads();
    s16x8 a0[4], a1[4];
    #pragma unroll
    for(int i=0;i<4;i++){ a0[i] = fragb(A0t, wm + i*16 + fr, quad); a1[i] = fragb(A1t, wm + i*16 + fr, quad); }
    #pragma unroll
    for(int j=0;j<4;j++){
      const s16x8 bf = fragb(Bt, wn + j*16 + fr, quad);
      #pragma unroll
      for(int i=0;i<4;i++){
        acc[i][j] = __builtin_amdgcn_mfma_f32_16x16x32_bf16(a0[i], bf, acc[i][j], 0,0,0);
        acc[i][j] = __builtin_amdgcn_mfma_f32_16x16x32_bf16(a1[i], bf, acc[i][j], 0,0,0);
      }
    }
    __syncthreads();
  }
  // LoRA-down phase: K=128 over RDhat (f16) @ wdbcat (f16)
  const Stage sAh = mk_stage(RDhat + (long)t0*128, 128, A0t, tid);
  const Stage sBh = mk_stage(wdbcat + (long)d0*128, 128, Bt, tid);
  for(int k0=0; k0<128; k0+=32){
    do_stage(sAh, k0); do_stage(sBh, k0);
    __syncthreads();
    f16x8 af[4];
    #pragma unroll
    for(int i=0;i<4;i++) af[i] = fragh(A0t, wm + i*16 + fr, quad);
    #pragma unroll
    for(int j=0;j<4;j++){
      const f16x8 bf = fragh(Bt, wn + j*16 + fr, quad);
      #pragma unroll
      for(int i=0;i<4;i++)
        acc[i][j] = __builtin_amdgcn_mfma_f32_16x16x32_f16(af[i], bf, acc[i][j], 0,0,0);
    }
    __syncthreads();
  }
  #pragma unroll
  for(int i=0;i<4;i++)
    #pragma unroll
    for(int j=0;j<4;j++){
      const int rbase = wm + i*16 + quad*4, col = wn + j*16 + fr;
      #pragma unroll
      for(int reg=0;reg<4;reg++)
        out[(long)(t0+rbase+reg)*DMODEL + d0 + col] = acc[i][j][reg];
    }
}

extern "C" void kernel_launch(void* const* d_in, const int* in_sizes, int n_in,
                              void* d_out, int out_size, void* d_ws, size_t ws_size,
                              hipStream_t stream){
  (void)in_sizes; (void)n_in; (void)out_size; (void)ws_size;
  const float* x      = (const float*)d_in[0];
  const float* gate_w = (const float*)d_in[1];
  const float* w_up   = (const float*)d_in[2];
  const float* w_gate = (const float*)d_in[3];
  const float* w_down = (const float*)d_in[4];
  const float* up_A   = (const float*)d_in[5];
  const float* up_B   = (const float*)d_in[6];
  const float* gate_A = (const float*)d_in[7];
  const float* gate_B = (const float*)d_in[8];
  const float* down_A = (const float*)d_in[9];
  const float* down_B = (const float*)d_in[10];
  float* out = (float*)d_out;

  char* ws = (char*)d_ws;
  size_t off = 0;
  auto alloc = [&](size_t bytes){ void* p = ws + off; off += (bytes + 255) & ~(size_t)255; return p; };
  short* xb     = (short*)alloc((size_t)TOKENS*DMODEL*2);
  short* wub    = (short*)alloc((size_t)DHID*DMODEL*2);
  short* wgb    = (short*)alloc((size_t)DHID*DMODEL*2);
  short* wdb    = (short*)alloc((size_t)DMODEL*DHID*2);
  short* acat   = (short*)alloc((size_t)256*DMODEL*2);
  short* daA    = (short*)alloc((size_t)128*DHID*2);
  short* upBh   = (short*)alloc((size_t)NEXP*DHID*RANK*2);
  short* gateBh = (short*)alloc((size_t)NEXP*DHID*RANK*2);
  short* wdbcat = (short*)alloc((size_t)DMODEL*128*2);
  unsigned short* ch = (unsigned short*)alloc((size_t)2*TOKENS*DHID*2);
  float* Rall   = (float*)alloc((size_t)TOKENS*256*4);
  float* RD     = (float*)alloc((size_t)TOKENS*2*128*4);
  __half* RDhat = (__half*)alloc((size_t)TOKENS*128*2);
  int*   sel    = (int*)alloc((size_t)TOKENS*2*4);
  float* topv   = (float*)alloc((size_t)TOKENS*2*4);
  float* cw     = (float*)alloc((size_t)TOKENS*2*4);

  (void)hipMemsetAsync(RD, 0, (size_t)TOKENS*2*128*4, stream);
  k_cast<<<40768, 256, 0, stream>>>(x, w_up, w_gate, w_down, up_A, gate_A, down_A,
                                    up_B, gate_B, down_B,
                                    xb, wub, wgb, wdb, acat, daA, upBh, gateBh, wdbcat);
  k_router<<<512, 256, 0, stream>>>(x, gate_w, sel, topv);
  k_softmax<<<4, 256, 0, stream>>>(topv, cw);
  k_rank<<<dim3(2,16), 256, 0, stream>>>(xb, acat, Rall);
  k_main<<<dim3(44,16), 256, 0, stream>>>(xb, wub, wgb, (const __half*)upBh, (const __half*)gateBh, Rall, sel, cw, ch);
  k_rd<<<dim3(16,16), 256, 0, stream>>>(ch, daA, RD);
  k_scatter<<<1024, 256, 0, stream>>>(RD, sel, RDhat);
  k_down<<<dim3(16,16), 256, 0, stream>>>(ch, wdb, (const short*)RDhat, wdbcat, out);
}